// Round 3
// baseline (5889.349 us; speedup 1.0000x reference)
//
#include <hip/hip_runtime.h>
#include <hip/hip_bf16.h>

// ---------------- problem constants ----------------
#define LDIM   1851   // L = TT - TINI - NH + 1
#define NFR    1000   // rows of F = [Uf(400); Yf(600)]
#define NAR    506    // rows of A = [Up(200); Yp(300); Yf_last(6)]
#define NCRP   1536   // padded rows of C = [F; A]
#define LDC    1856   // padded Hankel width
#define NG     1024   // padded G dim
#define NS     512    // padded S dim
#define NXC    1152   // padded X12 cols (1106 -> 1152)
#define LDMA   1120   // padded M_all cols (1100 -> 1120)
#define NBATCH 4096
#define NOUT   1000
#define INVDP  500000.0   // 1/(2*DELTA)

// ---------------- ws layout (bytes), lifetime-overlaid, total ~77.3 MB ----------------
#define OFF_C     ((size_t)0)
#define SZ_C      ((size_t)NCRP * LDC * 4)            // 11,403,264 ; C dead after k_gram
#define OFF_ILG   OFF_C                               // 1024*1024*8 (over C)
#define OFF_ILS   (OFF_C + 8388608)                   // 512*512*8 (over C)
#define OFF_GCC   (OFF_C + SZ_C)
#define SZ_GCC    ((size_t)NCRP * NCRP * 8)
#define OFF_G     (OFF_GCC + SZ_GCC)
#define SZ_G      ((size_t)NG * NG * 8)
#define OFF_TA    (OFF_G + SZ_G)
#define SZ_TA     ((size_t)NG * NS * 8)
#define OFF_S     (OFF_TA + SZ_TA)
#define SZ_S      ((size_t)NS * NS * 8)
#define OFF_X12   (OFF_S + SZ_S)
#define SZ_X12    ((size_t)NS * NXC * 8)
#define OFF_MRAW  (OFF_X12 + SZ_X12)
#define SZ_MRAW   ((size_t)NG * NXC * 4)              // 4,718,592
#define OFF_XB    OFF_MRAW                            // X12 backing (dead before MRAW written)
#define OFF_MALL  (OFF_MRAW + SZ_MRAW)
#define SZ_MALL   ((size_t)NG * LDMA * 4)             // 4,587,520 ; written at the very end
#define OFF_IDG   OFF_MALL                            // 16*4096*8 = 524,288
#define OFF_IDS   (OFF_MALL + 524288)                 // 8*4096*8  = 262,144
#define OFF_WG    (OFF_MALL + 786432)                 // 16*4096*8 = 524,288
#define OFF_WS    (OFF_MALL + 1310720)                // 8*4096*8  = 262,144
#define OFF_LS    (OFF_MALL + 1572864)                // 512*512*8 = 2,097,152 (ends 3.67MB < 4.59MB)
#define OFF_INALL (OFF_MALL + SZ_MALL)
#define SZ_INALL  ((size_t)LDMA * NBATCH * 4)         // 18,350,080 ; written late by transpose
#define OFF_TB    OFF_INALL                           // 1024*512*8 = 4,194,304
#define OFF_TINV  (OFF_INALL + 4194304)               // 512*512*8  = 2,097,152
#define OFF_LG    (OFF_INALL + 6291456)               // 1024*1024*8 = 8,388,608 (ends 14.68MB < 18.35MB)

__device__ __forceinline__ double dweight(int i, const float* q, const float* r) {
  return (i < 400) ? (double)r[i] : (double)q[i - 400];
}

// ---- 1) build C = [Uf; Yf; Up; Yp; Yf_last] (fp32, zero-padded) ----
__global__ __launch_bounds__(256) void k_build_C(const float* __restrict__ ud,
                                                 const float* __restrict__ yd,
                                                 float* __restrict__ C) {
  int j = blockIdx.x * 256 + threadIdx.x;
  int rr = blockIdx.y;
  if (j >= LDC) return;
  float v = 0.f;
  if (j < LDIM) {
    if (rr < 400)        v = ud[200 + rr + 4 * j];            // Uf
    else if (rr < 1000)  v = yd[300 + (rr - 400) + 6 * j];    // Yf
    else if (rr < 1200)  v = ud[(rr - 1000) + 4 * j];         // Up
    else if (rr < 1500)  v = yd[(rr - 1200) + 6 * j];         // Yp
    else if (rr < 1506)  v = yd[894 + (rr - 1500) + 6 * j];   // Yf[-P:]
  }
  C[(size_t)rr * LDC + j] = v;
}

// ---- 2) GCC = C * C^T, fp64 accumulation. 32x64 tiles (occupancy), mirror fill ----
__global__ __launch_bounds__(256) void k_gram(const float* __restrict__ C,
                                              double* __restrict__ GCC) {
  int ti = blockIdx.y;  // row tile /32 (0..47)
  int tj = blockIdx.x;  // col tile /64 (0..23)
  if (ti * 32 + 31 < tj * 64) return;  // fully-upper tiles skipped (mirror covers)
  __shared__ float As[32][33];
  __shared__ float Bs[64][33];
  int tid = threadIdx.x;
  int tr2 = (tid >> 4) * 2, tc4 = (tid & 15) * 4;
  double acc[2][4] = {};
  int i0 = ti * 32, j0 = tj * 64;
  for (int k0 = 0; k0 < LDC; k0 += 32) {
#pragma unroll
    for (int l = 0; l < 4; ++l) {
      int t = tid + l * 256;
      As[t >> 5][t & 31] = C[(size_t)(i0 + (t >> 5)) * LDC + k0 + (t & 31)];
    }
#pragma unroll
    for (int l = 0; l < 8; ++l) {
      int t = tid + l * 256;
      Bs[t >> 5][t & 31] = C[(size_t)(j0 + (t >> 5)) * LDC + k0 + (t & 31)];
    }
    __syncthreads();
#pragma unroll
    for (int kk = 0; kk < 32; ++kk) {
      double a[2], b[4];
#pragma unroll
      for (int i = 0; i < 2; ++i) a[i] = (double)As[tr2 + i][kk];
#pragma unroll
      for (int jx = 0; jx < 4; ++jx) b[jx] = (double)Bs[tc4 + jx][kk];
#pragma unroll
      for (int i = 0; i < 2; ++i)
#pragma unroll
        for (int jx = 0; jx < 4; ++jx) acc[i][jx] += a[i] * b[jx];
    }
    __syncthreads();
  }
#pragma unroll
  for (int i = 0; i < 2; ++i)
#pragma unroll
    for (int jx = 0; jx < 4; ++jx) {
      int gi = i0 + tr2 + i, gj = j0 + tc4 + jx;
      GCC[(size_t)gi * NCRP + gj] = acc[i][jx];
      if (gi > gj) GCC[(size_t)gj * NCRP + gi] = acc[i][jx];
    }
}

// ---- 3) G = GFF + (1e-6/d) I, padded with identity ----
__global__ __launch_bounds__(256) void k_copyG(const double* __restrict__ GCC,
                                               const float* __restrict__ q,
                                               const float* __restrict__ r,
                                               double* __restrict__ G) {
  int idx = blockIdx.x * 256 + threadIdx.x;
  int i = idx >> 10, j = idx & 1023;
  double v = (i < NFR && j < NFR) ? GCC[(size_t)i * NCRP + j] : 0.0;
  if (i == j) {
    if (i < NFR) v += 1e-6 / dweight(i, q, r);
    else v = 1.0;
  }
  G[idx] = v;
}

// ---- 4) TA rhs = GAF^T = F A^T (padded zeros) ----
__global__ __launch_bounds__(256) void k_copyTA(const double* __restrict__ GCC,
                                                double* __restrict__ TA) {
  int idx = blockIdx.x * 256 + threadIdx.x;
  int f = idx >> 9, a = idx & 511;
  TA[idx] = (f < NFR && a < NAR) ? GCC[(size_t)f * NCRP + 1000 + a] : 0.0;
}

// ---- core: factor 64x64 tile in LDS (sm stride 65, invd at sm+4160), then
//      write L to Ldst, write inv(L) to iLout, write W = iL^T iL to Wout ----
__device__ __forceinline__ void potrf_inv_w(double* sm, int tid,
                                            double* Ldst, int ld,
                                            double* iLout, double* Wout) {
  double* invd = sm + 4160;
  for (int c = 0; c < 64; ++c) {
    if (tid == 0) sm[c * 65 + c] = sqrt(sm[c * 65 + c]);
    __syncthreads();
    double piv = sm[c * 65 + c];
    for (int rr = c + 1 + tid; rr < 64; rr += 256) sm[rr * 65 + c] /= piv;
    __syncthreads();
    for (int t = tid; t < 64 * 64; t += 256) {
      int rr = t >> 6, jj = t & 63;
      if (rr > c && jj > c) sm[rr * 65 + jj] -= sm[rr * 65 + c] * sm[jj * 65 + c];
    }
    __syncthreads();
  }
#pragma unroll
  for (int l = 0; l < 16; ++l) {
    int t = tid + l * 256;
    Ldst[(size_t)(t >> 6) * ld + (t & 63)] = sm[(t >> 6) * 65 + (t & 63)];
  }
  __syncthreads();
  if (tid < 64) invd[tid] = 1.0 / sm[tid * 65 + tid];
  __syncthreads();
  if (tid < 64) {
    int c = tid;
    for (int r = c + 1; r < 64; ++r) {
      double s = sm[r * 65 + c] * invd[c];
      for (int j = c + 1; j < r; ++j) s += sm[r * 65 + j] * sm[c * 65 + j];  // sm[c][j]=iL[j][c]
      sm[c * 65 + r] = -s * invd[r];
    }
  }
  __syncthreads();
#pragma unroll
  for (int l = 0; l < 16; ++l) {
    int t = tid + l * 256;
    int r = t >> 6, c = t & 63;
    iLout[t] = (r < c) ? 0.0 : (r == c ? invd[r] : sm[c * 65 + r]);
  }
  for (int idx = tid; idx < 4096; idx += 256) {
    int r = idx >> 6, c = idx & 63;
    int k2 = r > c ? r : c;
    double s = 0.0;
    for (; k2 < 64; ++k2) {
      double ar = (k2 == r) ? invd[r] : sm[r * 65 + k2];
      double ac = (k2 == c) ? invd[c] : sm[c * 65 + k2];
      s += ar * ac;
    }
    Wout[idx] = s;
  }
}

// ---- initial potrf+inv+W of diag block (0,0) ----
__global__ __launch_bounds__(256) void k_potrf_inv0(double* __restrict__ M, int ld,
                                                    double* __restrict__ LG,
                                                    double* __restrict__ iL0,
                                                    double* __restrict__ W0) {
  __shared__ double sm[4160 + 64];
  int tid = threadIdx.x;
#pragma unroll
  for (int l = 0; l < 16; ++l) {
    int t = tid + l * 256;
    sm[(t >> 6) * 65 + (t & 63)] = M[(size_t)(t >> 6) * ld + (t & 63)];
  }
  __syncthreads();
  potrf_inv_w(sm, tid, LG, ld, iL0, W0);
}

// ---- fused panel step: L21 -> LG (j==0 blocks), trailing update A -= Ai*W*Aj^T,
//      and block 0 factors+inverts the next diagonal tile in-kernel ----
#define FS1(r, c) sm[(r) * 65 + (c)]
#define FS2(r, c) sm[4160 + (r) * 33 + (c)]
__global__ __launch_bounds__(256) void k_chol_fused(double* __restrict__ M, int ld, int k,
                                                    const double* __restrict__ iLcur,
                                                    const double* __restrict__ Wcur,
                                                    double* __restrict__ LG,
                                                    double* __restrict__ iLnext,
                                                    double* __restrict__ Wnext) {
  __shared__ double sm[6272];  // 50.2 KB
  int tid = threadIdx.x;
  int t = blockIdx.x;
  int i = (int)((sqrtf(8.f * t + 1.f) - 1.f) * 0.5f);
  while ((i + 1) * (i + 2) / 2 <= t) ++i;
  while (i * (i + 1) / 2 > t) --i;
  int j = t - i * (i + 1) / 2;
  int tr4 = (tid >> 4) * 4, tc4 = (tid & 15) * 4;
  int rowAi = k + 64 + i * 64, rowAj = k + 64 + j * 64;

  // Phase A (j==0): Li = Ai * iL^T  -> LG panel
  if (j == 0) {
#pragma unroll
    for (int l = 0; l < 16; ++l) { int t2 = tid + l * 256; FS1(t2 >> 6, t2 & 63) = iLcur[t2]; }
    __syncthreads();
    double li[4][4] = {};
    for (int k0 = 0; k0 < 64; k0 += 32) {
#pragma unroll
      for (int l = 0; l < 8; ++l) {
        int t2 = tid + l * 256;
        FS2(t2 >> 5, t2 & 31) = M[(size_t)(rowAi + (t2 >> 5)) * ld + k + k0 + (t2 & 31)];
      }
      __syncthreads();
#pragma unroll
      for (int mm = 0; mm < 32; ++mm) {
        double a[4], b[4];
#pragma unroll
        for (int i2 = 0; i2 < 4; ++i2) a[i2] = FS2(tr4 + i2, mm);
#pragma unroll
        for (int j2 = 0; j2 < 4; ++j2) b[j2] = FS1(tc4 + j2, k0 + mm);
#pragma unroll
        for (int i2 = 0; i2 < 4; ++i2)
#pragma unroll
          for (int j2 = 0; j2 < 4; ++j2) li[i2][j2] += a[i2] * b[j2];
      }
      __syncthreads();
    }
#pragma unroll
    for (int i2 = 0; i2 < 4; ++i2)
#pragma unroll
      for (int j2 = 0; j2 < 4; ++j2)
        LG[(size_t)(rowAi + tr4 + i2) * ld + k + tc4 + j2] = li[i2][j2];
  }
  __syncthreads();

  // Phase B: trailing tile (i,j) -= Ai * W * Aj^T
#pragma unroll
  for (int l = 0; l < 16; ++l) { int t2 = tid + l * 256; FS1(t2 >> 6, t2 & 63) = Wcur[t2]; }
  __syncthreads();
  double acc[4][4] = {};
  for (int k0 = 0; k0 < 64; k0 += 32) {  // D1 = W * Aj^T
#pragma unroll
    for (int l = 0; l < 8; ++l) {
      int t2 = tid + l * 256;
      FS2(t2 >> 5, t2 & 31) = M[(size_t)(rowAj + (t2 >> 5)) * ld + k + k0 + (t2 & 31)];
    }
    __syncthreads();
#pragma unroll
    for (int mm = 0; mm < 32; ++mm) {
      double a[4], b[4];
#pragma unroll
      for (int i2 = 0; i2 < 4; ++i2) a[i2] = FS1(tr4 + i2, k0 + mm);
#pragma unroll
      for (int j2 = 0; j2 < 4; ++j2) b[j2] = FS2(tc4 + j2, mm);
#pragma unroll
      for (int i2 = 0; i2 < 4; ++i2)
#pragma unroll
        for (int j2 = 0; j2 < 4; ++j2) acc[i2][j2] += a[i2] * b[j2];
    }
    __syncthreads();
  }
#pragma unroll
  for (int i2 = 0; i2 < 4; ++i2)  // stash D1 in FS1 (W dead)
#pragma unroll
    for (int j2 = 0; j2 < 4; ++j2) FS1(tr4 + i2, tc4 + j2) = acc[i2][j2];
  __syncthreads();
  double acc2[4][4] = {};
  for (int k0 = 0; k0 < 64; k0 += 32) {  // C = Ai * D1
#pragma unroll
    for (int l = 0; l < 8; ++l) {
      int t2 = tid + l * 256;
      FS2(t2 >> 5, t2 & 31) = M[(size_t)(rowAi + (t2 >> 5)) * ld + k + k0 + (t2 & 31)];
    }
    __syncthreads();
#pragma unroll
    for (int mm = 0; mm < 32; ++mm) {
      double a[4], b[4];
#pragma unroll
      for (int i2 = 0; i2 < 4; ++i2) a[i2] = FS2(tr4 + i2, mm);
#pragma unroll
      for (int j2 = 0; j2 < 4; ++j2) b[j2] = FS1(k0 + mm, tc4 + j2);
#pragma unroll
      for (int i2 = 0; i2 < 4; ++i2)
#pragma unroll
        for (int j2 = 0; j2 < 4; ++j2) acc2[i2][j2] += a[i2] * b[j2];
    }
    __syncthreads();
  }
  double upd[4][4];
#pragma unroll
  for (int i2 = 0; i2 < 4; ++i2)
#pragma unroll
    for (int j2 = 0; j2 < 4; ++j2) {
      size_t off = (size_t)(rowAi + tr4 + i2) * ld + rowAj + tc4 + j2;
      upd[i2][j2] = M[off] - acc2[i2][j2];
      M[off] = upd[i2][j2];
    }

  // Phase C (block 0 = tile (0,0) = next diagonal): factor + invert in-kernel
  if (blockIdx.x == 0) {
    __syncthreads();
#pragma unroll
    for (int i2 = 0; i2 < 4; ++i2)
#pragma unroll
      for (int j2 = 0; j2 < 4; ++j2) FS1(tr4 + i2, tc4 + j2) = upd[i2][j2];
    __syncthreads();
    potrf_inv_w(sm, tid, LG + (size_t)(k + 64) * ld + (k + 64), ld, iLnext, Wnext);
  }
}

// ---- generic fp64 GEMM cores (64x64 C tile, 4x4 micro) ----
__device__ __forceinline__ void dgemm_nn_core(const double* __restrict__ A, int lda,
                                              const double* __restrict__ B, int ldb,
                                              double* __restrict__ C, int ldc,
                                              int kBeg, int kEnd, double alpha) {
  __shared__ double As[64][33];
  __shared__ double Bs[32][65];
  int tid = threadIdx.x;
  int tr4 = (tid >> 4) * 4, tc4 = (tid & 15) * 4;
  double acc[4][4] = {};
  for (int k0 = kBeg; k0 < kEnd; k0 += 32) {
#pragma unroll
    for (int l = 0; l < 8; ++l) {
      int t = tid + l * 256;
      As[t >> 5][t & 31] = A[(size_t)(t >> 5) * lda + k0 + (t & 31)];
    }
#pragma unroll
    for (int l = 0; l < 8; ++l) {
      int t = tid + l * 256;
      Bs[t >> 6][t & 63] = B[(size_t)(k0 + (t >> 6)) * ldb + (t & 63)];
    }
    __syncthreads();
#pragma unroll
    for (int kk = 0; kk < 32; ++kk) {
      double a[4], b[4];
#pragma unroll
      for (int i = 0; i < 4; ++i) a[i] = As[tr4 + i][kk];
#pragma unroll
      for (int jx = 0; jx < 4; ++jx) b[jx] = Bs[kk][tc4 + jx];
#pragma unroll
      for (int i = 0; i < 4; ++i)
#pragma unroll
        for (int jx = 0; jx < 4; ++jx) acc[i][jx] += a[i] * b[jx];
    }
    __syncthreads();
  }
#pragma unroll
  for (int i = 0; i < 4; ++i)
#pragma unroll
    for (int jx = 0; jx < 4; ++jx)
      C[(size_t)(tr4 + i) * ldc + tc4 + jx] = alpha * acc[i][jx];
}

__device__ __forceinline__ void dgemm_tn_core(const double* __restrict__ A, int lda,
                                              const double* __restrict__ B, int ldb,
                                              double* __restrict__ C, int ldc,
                                              int kBeg, int kEnd, double alpha) {
  __shared__ double Ls[32][65];
  __shared__ double Bs[32][65];
  int tid = threadIdx.x;
  int tr4 = (tid >> 4) * 4, tc4 = (tid & 15) * 4;
  double acc[4][4] = {};
  for (int k0 = kBeg; k0 < kEnd; k0 += 32) {
#pragma unroll
    for (int l = 0; l < 8; ++l) {
      int t = tid + l * 256;
      int jj = t >> 6, rr = t & 63;
      Ls[jj][rr] = A[(size_t)(k0 + jj) * lda + rr];
    }
#pragma unroll
    for (int l = 0; l < 8; ++l) {
      int t = tid + l * 256;
      Bs[t >> 6][t & 63] = B[(size_t)(k0 + (t >> 6)) * ldb + (t & 63)];
    }
    __syncthreads();
#pragma unroll
    for (int kk = 0; kk < 32; ++kk) {
      double a[4], b[4];
#pragma unroll
      for (int i = 0; i < 4; ++i) a[i] = Ls[kk][tr4 + i];
#pragma unroll
      for (int jx = 0; jx < 4; ++jx) b[jx] = Bs[kk][tc4 + jx];
#pragma unroll
      for (int i = 0; i < 4; ++i)
#pragma unroll
        for (int jx = 0; jx < 4; ++jx) acc[i][jx] += a[i] * b[jx];
    }
    __syncthreads();
  }
#pragma unroll
  for (int i = 0; i < 4; ++i)
#pragma unroll
    for (int jx = 0; jx < 4; ++jx)
      C[(size_t)(tr4 + i) * ldc + tc4 + jx] = alpha * acc[i][jx];
}

__global__ __launch_bounds__(256) void k_dgemm_nn(const double* __restrict__ A, int lda,
                                                  const double* __restrict__ B, int ldb,
                                                  double* __restrict__ C, int ldc,
                                                  int K, int tri, double alpha) {
  int bi = blockIdx.y, bj = blockIdx.x;
  int kEnd = tri ? ((bi + 1) * 64 < K ? (bi + 1) * 64 : K) : K;
  dgemm_nn_core(A + (size_t)bi * 64 * lda, lda, B + bj * 64, ldb,
                C + (size_t)bi * 64 * ldc + bj * 64, ldc, 0, kEnd, alpha);
}

__global__ __launch_bounds__(256) void k_dgemm_tn(const double* __restrict__ A, int lda,
                                                  const double* __restrict__ B, int ldb,
                                                  double* __restrict__ C, int ldc,
                                                  int K, int tri, double alpha) {
  int bi = blockIdx.y, bj = blockIdx.x;
  int kBeg = tri ? bi * 64 : 0;
  dgemm_tn_core(A + bi * 64, lda, B + bj * 64, ldb,
                C + (size_t)bi * 64 * ldc + bj * 64, ldc, kBeg, K, alpha);
}

// ---- iL assembly: diag-64 inverses in, zeros elsewhere ----
__global__ __launch_bounds__(256) void k_init_iL(double* __restrict__ iL, int nShift,
                                                 const double* __restrict__ IDIAG) {
  int idx = blockIdx.x * 256 + threadIdx.x;
  int n = 1 << nShift;
  int i = idx >> nShift, j = idx & (n - 1);
  int d = i >> 6;
  double v = 0.0;
  if ((j >> 6) == d) v = IDIAG[(size_t)d * 4096 + (i & 63) * 64 + (j & 63)];
  iL[idx] = v;
}

// ---- D&C inverse levels: T_p = L21 * iL11 ; then iL21 = -iL22 * T_p ----
__global__ __launch_bounds__(256) void k_ilv_tmp(const double* __restrict__ L, int ldl,
                                                 const double* __restrict__ iL, int ldi,
                                                 double* __restrict__ T, int half) {
  int p = blockIdx.z, bi = blockIdx.y, bj = blockIdx.x;
  int base = p * 2 * half;
  dgemm_nn_core(L + (size_t)(base + half + bi * 64) * ldl + base, ldl,
                iL + (size_t)base * ldi + base + bj * 64, ldi,
                T + (size_t)p * half * half + (size_t)bi * 64 * half + bj * 64, half,
                0, half, 1.0);
}

__global__ __launch_bounds__(256) void k_ilv_fin(double* __restrict__ iL, int ldi,
                                                 const double* __restrict__ T, int half) {
  int p = blockIdx.z, bi = blockIdx.y, bj = blockIdx.x;
  int base = p * 2 * half;
  dgemm_nn_core(iL + (size_t)(base + half + bi * 64) * ldi + base + half, ldi,
                T + (size_t)p * half * half + bj * 64, half,
                iL + (size_t)(base + half + bi * 64) * ldi + base + bj * 64, ldi,
                0, half, -1.0);
}

// ---- S = (GAA - GAF * TA) / (2*DELTA), identity-padded ----
__global__ __launch_bounds__(256) void k_buildS(const double* __restrict__ GCC,
                                                const double* __restrict__ TA,
                                                double* __restrict__ S) {
  __shared__ double Ga[64][33];
  __shared__ double Tb[32][65];
  int tid = threadIdx.x;
  int tr4 = (tid >> 4) * 4, tc4 = (tid & 15) * 4;
  int a0 = blockIdx.y * 64, b0 = blockIdx.x * 64;
  double acc[4][4] = {};
  for (int f0 = 0; f0 < NG; f0 += 32) {
#pragma unroll
    for (int l = 0; l < 8; ++l) {
      int t = tid + l * 256;
      Ga[t >> 5][t & 31] = GCC[(size_t)(1000 + a0 + (t >> 5)) * NCRP + f0 + (t & 31)];
    }
#pragma unroll
    for (int l = 0; l < 8; ++l) {
      int t = tid + l * 256;
      Tb[t >> 6][t & 63] = TA[(size_t)(f0 + (t >> 6)) * NS + b0 + (t & 63)];
    }
    __syncthreads();
#pragma unroll
    for (int kk = 0; kk < 32; ++kk) {
      double a[4], b[4];
#pragma unroll
      for (int i = 0; i < 4; ++i) a[i] = Ga[tr4 + i][kk];
#pragma unroll
      for (int jx = 0; jx < 4; ++jx) b[jx] = Tb[kk][tc4 + jx];
#pragma unroll
      for (int i = 0; i < 4; ++i)
#pragma unroll
        for (int jx = 0; jx < 4; ++jx) acc[i][jx] += a[i] * b[jx];
    }
    __syncthreads();
  }
#pragma unroll
  for (int i = 0; i < 4; ++i)
#pragma unroll
    for (int jx = 0; jx < 4; ++jx) {
      int a = a0 + tr4 + i, b = b0 + tc4 + jx;
      double v;
      if (a < NAR && b < NAR)
        v = (GCC[(size_t)(1000 + a) * NCRP + 1000 + b] - acc[i][jx]) * INVDP;
      else
        v = (a == b) ? 1.0 : 0.0;
      S[(size_t)a * NS + b] = v;
    }
}

// ---- X12 rhs = [TAq^T | I] ----
__global__ __launch_bounds__(256) void k_build_x12rhs(const double* __restrict__ TA,
                                                      double* __restrict__ X12) {
  int c = blockIdx.x * 256 + threadIdx.x;
  int a = blockIdx.y;
  if (c >= NXC) return;
  double v = 0.0;
  if (a < NAR) {
    if (c < 600) v = TA[(size_t)(400 + c) * NS + a];
    else if (c < 1106) v = (a == (c - 600)) ? 1.0 : 0.0;
  }
  X12[(size_t)a * NXC + c] = v;
}

// ---- Mraw = sign * (TA * X12) / (2 d_o)  (fp32 output) ----
__global__ __launch_bounds__(256) void k_gemm_M(const double* __restrict__ TA,
                                                const double* __restrict__ X12,
                                                const float* __restrict__ q,
                                                const float* __restrict__ r,
                                                float* __restrict__ Mraw) {
  __shared__ double Ga[64][33];
  __shared__ double Xb[32][65];
  int tid = threadIdx.x;
  int tr4 = (tid >> 4) * 4, tc4 = (tid & 15) * 4;
  int o0 = blockIdx.y * 64, c0 = blockIdx.x * 64;
  double acc[4][4] = {};
  for (int k0 = 0; k0 < NS; k0 += 32) {
#pragma unroll
    for (int l = 0; l < 8; ++l) {
      int t = tid + l * 256;
      Ga[t >> 5][t & 31] = TA[(size_t)(o0 + (t >> 5)) * NS + k0 + (t & 31)];
    }
#pragma unroll
    for (int l = 0; l < 8; ++l) {
      int t = tid + l * 256;
      Xb[t >> 6][t & 63] = X12[(size_t)(k0 + (t >> 6)) * NXC + c0 + (t & 63)];
    }
    __syncthreads();
#pragma unroll
    for (int kk = 0; kk < 32; ++kk) {
      double a[4], b[4];
#pragma unroll
      for (int i = 0; i < 4; ++i) a[i] = Ga[tr4 + i][kk];
#pragma unroll
      for (int jx = 0; jx < 4; ++jx) b[jx] = Xb[kk][tc4 + jx];
#pragma unroll
      for (int i = 0; i < 4; ++i)
#pragma unroll
        for (int jx = 0; jx < 4; ++jx) acc[i][jx] += a[i] * b[jx];
    }
    __syncthreads();
  }
#pragma unroll
  for (int i = 0; i < 4; ++i)
#pragma unroll
    for (int jx = 0; jx < 4; ++jx) {
      int o = o0 + tr4 + i, col = c0 + tc4 + jx;
      float v = 0.f;
      if (o < NFR) {
        double scale = 1.0 / (2.0 * dweight(o, q, r));
        double tt = acc[i][jx] * scale;
        v = (float)((col < 600) ? -tt : tt);
      }
      Mraw[(size_t)o * NXC + col] = v;
    }
}

// ---- assemble final fp32 map: identity insert + ref_last fold ----
__global__ __launch_bounds__(256) void k_assemble_M(const float* __restrict__ Mraw,
                                                    float* __restrict__ Mall) {
  int j = blockIdx.x * 256 + threadIdx.x;
  int o = blockIdx.y;
  if (j >= LDMA) return;
  float v = 0.f;
  if (j < 600) {
    v = Mraw[(size_t)o * NXC + j];
    if (o == 400 + j) v += 1.0f;
    if (j >= 594) v += Mraw[(size_t)o * NXC + 1100 + (j - 594)];
  } else if (j < 1100) {
    v = Mraw[(size_t)o * NXC + j];
  }
  Mall[(size_t)o * LDMA + j] = v;
}

// ---- transpose batch inputs into IN_all [LDMA][NBATCH] ----
__global__ __launch_bounds__(256) void k_transpose_in(const float* __restrict__ ref,
                                                      const float* __restrict__ ui,
                                                      const float* __restrict__ yi,
                                                      float* __restrict__ INall) {
  __shared__ float t[32][33];
  int tx = threadIdx.x & 31, ty = threadIdx.x >> 5;  // 32 x 8
  int n0 = blockIdx.x * 32, j0 = blockIdx.y * 32;
#pragma unroll
  for (int p = 0; p < 4; ++p) {
    int nb = n0 + ty + p * 8;
    int j = j0 + tx;
    float v = 0.f;
    if (j < 600)        v = ref[(size_t)nb * 600 + j];
    else if (j < 800)   v = ui[(size_t)nb * 200 + (j - 600)];
    else if (j < 1100)  v = yi[(size_t)nb * 300 + (j - 800)];
    t[ty + p * 8][tx] = v;
  }
  __syncthreads();
#pragma unroll
  for (int p = 0; p < 4; ++p) {
    INall[(size_t)(j0 + ty + p * 8) * NBATCH + n0 + tx] = t[tx][ty + p * 8];
  }
}

// ---- final batch GEMM: OUT[1000][4096] = Mall[1000][1120] * INall[1120][4096] ----
__global__ __launch_bounds__(256) void k_gemm_out(const float* __restrict__ Mall,
                                                  const float* __restrict__ INall,
                                                  float* __restrict__ out) {
  __shared__ float As[32][132];
  __shared__ float Bs[32][132];
  int tid = threadIdx.x;
  int tr = tid >> 4, tc = tid & 15;
  int m0 = blockIdx.y * 128, n0 = blockIdx.x * 128;
  float acc[8][8] = {};
  for (int k0 = 0; k0 < LDMA; k0 += 32) {
#pragma unroll
    for (int l = 0; l < 16; ++l) {
      int t = tid + l * 256;
      int rr = t >> 5, cc = t & 31;
      As[cc][rr] = Mall[(size_t)(m0 + rr) * LDMA + k0 + cc];
    }
#pragma unroll
    for (int l = 0; l < 16; ++l) {
      int t = tid + l * 256;
      int rr = t >> 7, cc = t & 127;
      Bs[rr][cc] = INall[(size_t)(k0 + rr) * NBATCH + n0 + cc];
    }
    __syncthreads();
#pragma unroll
    for (int kk = 0; kk < 32; ++kk) {
      float4 a0 = *(const float4*)&As[kk][tr * 4];
      float4 a1 = *(const float4*)&As[kk][64 + tr * 4];
      float4 b0 = *(const float4*)&Bs[kk][tc * 4];
      float4 b1 = *(const float4*)&Bs[kk][64 + tc * 4];
      float av[8] = {a0.x, a0.y, a0.z, a0.w, a1.x, a1.y, a1.z, a1.w};
      float bv[8] = {b0.x, b0.y, b0.z, b0.w, b1.x, b1.y, b1.z, b1.w};
#pragma unroll
      for (int i = 0; i < 8; ++i)
#pragma unroll
        for (int jx = 0; jx < 8; ++jx) acc[i][jx] += av[i] * bv[jx];
    }
    __syncthreads();
  }
#pragma unroll
  for (int ih = 0; ih < 2; ++ih)
#pragma unroll
    for (int i = 0; i < 4; ++i) {
      int o = m0 + ih * 64 + tr * 4 + i;
      if (o < NOUT) {
#pragma unroll
        for (int jh = 0; jh < 2; ++jh) {
          float4 v = make_float4(acc[ih * 4 + i][jh * 4 + 0], acc[ih * 4 + i][jh * 4 + 1],
                                 acc[ih * 4 + i][jh * 4 + 2], acc[ih * 4 + i][jh * 4 + 3]);
          *(float4*)&out[(size_t)o * NBATCH + n0 + jh * 64 + tc * 4] = v;
        }
      }
    }
}

extern "C" void kernel_launch(void* const* d_in, const int* in_sizes, int n_in,
                              void* d_out, int out_size, void* d_ws, size_t ws_size,
                              hipStream_t stream) {
  const float* ud  = (const float*)d_in[0];
  const float* yd  = (const float*)d_in[1];
  const float* qv  = (const float*)d_in[2];
  const float* rv  = (const float*)d_in[3];
  const float* ref = (const float*)d_in[4];
  const float* ui  = (const float*)d_in[5];
  const float* yi  = (const float*)d_in[6];
  float* out = (float*)d_out;
  char* w = (char*)d_ws;

  float*  C    = (float*)(w + OFF_C);
  double* GCC  = (double*)(w + OFF_GCC);
  double* G    = (double*)(w + OFF_G);
  double* TA   = (double*)(w + OFF_TA);
  double* S    = (double*)(w + OFF_S);
  double* X12  = (double*)(w + OFF_X12);
  float*  MRAW = (float*)(w + OFF_MRAW);
  float*  MALL = (float*)(w + OFF_MALL);
  float*  INA  = (float*)(w + OFF_INALL);
  double* ILG  = (double*)(w + OFF_ILG);
  double* ILS  = (double*)(w + OFF_ILS);
  double* IDG  = (double*)(w + OFF_IDG);
  double* IDS  = (double*)(w + OFF_IDS);
  double* WG   = (double*)(w + OFF_WG);
  double* WS   = (double*)(w + OFF_WS);
  double* LG   = (double*)(w + OFF_LG);
  double* LS   = (double*)(w + OFF_LS);
  double* TB   = (double*)(w + OFF_TB);
  double* TINV = (double*)(w + OFF_TINV);
  double* XB   = (double*)(w + OFF_XB);

  // 1) Hankel blocks, Gram, G and T_A rhs
  k_build_C<<<dim3(8, NCRP), 256, 0, stream>>>(ud, yd, C);
  k_gram<<<dim3(24, 48), 256, 0, stream>>>(C, GCC);
  k_copyG<<<dim3(NG * NG / 256), 256, 0, stream>>>(GCC, qv, rv, G);
  k_copyTA<<<dim3(NG * NS / 256), 256, 0, stream>>>(GCC, TA);

  // 2) Cholesky of G: 16 kernels total (initial + 15 fused panel steps)
  k_potrf_inv0<<<1, 256, 0, stream>>>(G, NG, LG, IDG, WG);
  for (int p = 0; p < 15; ++p) {
    int nb = 15 - p;
    k_chol_fused<<<dim3(nb * (nb + 1) / 2), 256, 0, stream>>>(
        G, NG, p * 64, IDG + (size_t)p * 4096, WG + (size_t)p * 4096, LG,
        IDG + (size_t)(p + 1) * 4096, WG + (size_t)(p + 1) * 4096);
  }

  // 3) iL_G via divide&conquer (log-depth), then T_A = iL^T iL GAF^T (2 GEMMs)
  k_init_iL<<<dim3(NG * NG / 256), 256, 0, stream>>>(ILG, 10, IDG);
  for (int lv = 0; lv < 4; ++lv) {
    int half = 64 << lv, pairs = NG / (2 * half);
    dim3 gt(half / 64, half / 64, pairs);
    k_ilv_tmp<<<gt, 256, 0, stream>>>(LG, NG, ILG, NG, TINV, half);
    k_ilv_fin<<<gt, 256, 0, stream>>>(ILG, NG, TINV, half);
  }
  k_dgemm_nn<<<dim3(NS / 64, NG / 64), 256, 0, stream>>>(ILG, NG, TA, NS, TB, NS, NG, 1, 1.0);
  k_dgemm_tn<<<dim3(NS / 64, NG / 64), 256, 0, stream>>>(ILG, NG, TB, NS, TA, NS, NG, 1, 1.0);

  // 4) S, its Cholesky (8 kernels) + iL_S
  k_buildS<<<dim3(8, 8), 256, 0, stream>>>(GCC, TA, S);
  k_potrf_inv0<<<1, 256, 0, stream>>>(S, NS, LS, IDS, WS);
  for (int p = 0; p < 7; ++p) {
    int nb = 7 - p;
    k_chol_fused<<<dim3(nb * (nb + 1) / 2), 256, 0, stream>>>(
        S, NS, p * 64, IDS + (size_t)p * 4096, WS + (size_t)p * 4096, LS,
        IDS + (size_t)(p + 1) * 4096, WS + (size_t)(p + 1) * 4096);
  }
  k_init_iL<<<dim3(NS * NS / 256), 256, 0, stream>>>(ILS, 9, IDS);
  for (int lv = 0; lv < 3; ++lv) {
    int half = 64 << lv, pairs = NS / (2 * half);
    dim3 gt(half / 64, half / 64, pairs);
    k_ilv_tmp<<<gt, 256, 0, stream>>>(LS, NS, ILS, NS, TINV, half);
    k_ilv_fin<<<gt, 256, 0, stream>>>(ILS, NS, TINV, half);
  }

  // 5) X12 = S^{-1} [TAq^T | I]  (2 GEMMs)
  k_build_x12rhs<<<dim3(5, NS), 256, 0, stream>>>(TA, X12);
  k_dgemm_nn<<<dim3(NXC / 64, NS / 64), 256, 0, stream>>>(ILS, NS, X12, NXC, XB, NXC, NS, 1, 1.0);
  k_dgemm_tn<<<dim3(NXC / 64, NS / 64), 256, 0, stream>>>(ILS, NS, XB, NXC, X12, NXC, NS, 1, 1.0);

  // 6) solution maps + batch GEMM
  k_gemm_M<<<dim3(NXC / 64, NG / 64), 256, 0, stream>>>(TA, X12, qv, rv, MRAW);
  k_assemble_M<<<dim3(5, NG), 256, 0, stream>>>(MRAW, MALL);
  k_transpose_in<<<dim3(NBATCH / 32, LDMA / 32), 256, 0, stream>>>(ref, ui, yi, INA);
  k_gemm_out<<<dim3(NBATCH / 128, NG / 128), 256, 0, stream>>>(MALL, INA, out);
}